// Round 9
// baseline (1820.436 us; speedup 1.0000x reference)
//
#include <hip/hip_runtime.h>
#include <math.h>

// ---------------------------------------------------------------------------
// HFPS: CNN (4 residual blocks, circular 3x3 conv, 48x48, 64ch) ->
//       A = [[Fvv[n][:,n], Fvh_n],[-Fvh_n^T, Fhh_a]] (1048x1048 skew) ->
//       sign(Pf(A)), log|Pf(A)| + log_J
// Pfaffian via unpivoted blocked skew LDL^T with 2x2 pivots, fp64.
//   Pf = prod(t_p); log|Pf| = sum log|t_p| = 0.5*slogdet(A).
//
// R9: PER-PHASE KERNEL LAUNCHES (R5-R8 post-mortem: single-kernel coop
// versions pinned at 1.07-1.26 ms across wildly different traffic/sync
// designs; phase model under-predicts 3x and cannot be localized inside one
// dispatch). Kernel boundaries = free coherent device-wide sync; A stays
// L2/LLC-hot (8.8 MB); rocprof times every phase. No device-scope atomics.
//   k_buildA: lower triangle of A only (upper never read).
//   k_panelD (1 block): 64x64 diag factorization, register-tile 4x4/thread,
//     pivot divide pipelined one step ahead; writes hist (invt + scaled
//     pivot-column history) + atomicAdd log/sign partials.
//   k_panelR (m/4 blocks): wave-per-row 32-step shfl chain on panel cols.
//   k_trail (nt(nt+1)/2 blocks): 64x64 lower-triangle tiles of rank-64
//     Schur update; P staged via LDS in two l-chunks; conflict-free layout.
//
// Workspace layout:
//   0:    lacc (double)  8: nneg (int)   1024: logJ acc   1088: nidx[1024]
//   8192: hist (4128 doubles = 33 KB; aliases dead CNN scratch timing-wise)
//   49152: tbuf/ybuf/hbuf0/hbuf1 (4 x 64*2304 fp32)  [CNN]
//   2408448: A (1048*1048 fp64 = 8.79 MB)
// ---------------------------------------------------------------------------

#define NPIX 2304          // 48*48
#define MSZ  4608          // 2*48*48
#define NOCC 1024
#define NHID 24
#define PF_N 1048          // NOCC + 2*NHID

__device__ __forceinline__ float gelu_f(float v){
  // jax.nn.gelu approximate=True (tanh form)
  float v3 = v*v*v;
  return 0.5f*v*(1.0f + tanhf(0.7978845608028654f*(v + 0.044715f*v3)));
}

// ---- occupied-site indices (sorted), x[i]==1.0f exactly ----
__global__ void k_find_n(const float* __restrict__ x, int* __restrict__ nidx){
  __shared__ int cnt[256];
  __shared__ int off[256];
  int t = threadIdx.x;
  int c = 0;
  for (int k = 0; k < 18; k++) c += (x[t*18+k] == 1.0f) ? 1 : 0;
  cnt[t] = c;
  __syncthreads();
  if (t == 0){ int s = 0; for (int q=0;q<256;q++){ off[q]=s; s+=cnt[q]; } }
  __syncthreads();
  int o = off[t];
  for (int k = 0; k < 18; k++){
    int idx = t*18+k;
    if (x[idx] == 1.0f) nidx[o++] = idx;
  }
}

// ---- elementwise pre-op: t = [gelu](h*scale) ----
__global__ void k_pre(const float* __restrict__ in, float* __restrict__ outp,
                      int count, int dogelu, float scale){
  int g = blockIdx.x*256 + threadIdx.x;
  if (g >= count) return;
  float v = in[g]*scale;
  if (dogelu) v = gelu_f(v);
  outp[g] = v;
}

// ---- circular 3x3 conv, 64 out channels, fused bias/gelu/residual/scale ----
__global__ __launch_bounds__(256) void k_conv(const float* __restrict__ in,
      const float* __restrict__ wgt, const float* __restrict__ bias,
      const float* __restrict__ res, float* __restrict__ outp,
      int cin, int resmode, int dogelu, float scale){
  int c = blockIdx.x / 9;
  int p = (blockIdx.x % 9)*256 + threadIdx.x;
  int y = p / 48, x = p - y*48;
  int ym = ((y+47)%48)*48, y0 = y*48, yp = ((y+1)%48)*48;
  int xm = (x+47)%48, xq = (x+1)%48;
  float s = 0.f;
  const float* wp = wgt + c*cin*9;
  for (int ci = 0; ci < cin; ci++){
    const float* b_ = in + ci*NPIX;
    s += b_[ym+xm]*wp[0] + b_[ym+x]*wp[1] + b_[ym+xq]*wp[2]
       + b_[y0+xm]*wp[3] + b_[y0+x]*wp[4] + b_[y0+xq]*wp[5]
       + b_[yp+xm]*wp[6] + b_[yp+x]*wp[7] + b_[yp+xq]*wp[8];
    wp += 9;
  }
  if (bias) s += bias[c];
  if (dogelu) s = gelu_f(s);
  if (resmode == 1) s += res[c*NPIX + p];
  else if (resmode == 2) s += res[(c>>5)*NPIX + p];  // jnp.repeat(res,32,axis=0)
  s *= scale;
  outp[c*NPIX + p] = s;
}

// ---- log_J = sum over channels 48..63 of final h ----
__global__ void k_logJ(const float* __restrict__ hfin, double* __restrict__ acc){
  int g = blockIdx.x*256 + threadIdx.x;   // 144*256 = 36864
  double v = (double)hfin[48*NPIX + g];
  for (int o = 32; o > 0; o >>= 1) v += __shfl_down(v, o, 64);
  __shared__ double wsum[4];
  int lane = threadIdx.x & 63, wv = threadIdx.x >> 6;
  if (lane == 0) wsum[wv] = v;
  __syncthreads();
  if (threadIdx.x == 0) atomicAdd(acc, wsum[0]+wsum[1]+wsum[2]+wsum[3]);
}

// F_vh[m][r] = out[2r + (m>=2304)][m % 2304]
__device__ __forceinline__ double fvh_val(const float* h, int m, int r){
  int s = (m >= NPIX) ? 1 : 0;
  int p = m - s*NPIX;
  return (double)h[(2*r+s)*NPIX + p];
}

// ---- assemble skew matrix A, LOWER TRIANGLE ONLY (upper never read) ----
__global__ void k_buildA(const float* __restrict__ Fvv, const float* __restrict__ Fhh,
                         const float* __restrict__ hfin, const int* __restrict__ nidx,
                         double* __restrict__ A){
  int g = blockIdx.x*256 + threadIdx.x;
  if (g >= PF_N*PF_N) return;
  int i = g / PF_N, j = g - i*PF_N;
  if (j >= i) return;
  double v;
  if (i < NOCC){
    int ni = nidx[i], nj = nidx[j];
    v = 0.5*((double)Fvv[(size_t)ni*MSZ + nj] - (double)Fvv[(size_t)nj*MSZ + ni]);
  } else if (j < NOCC){
    v = -fvh_val(hfin, nidx[j], i - NOCC);
  } else {
    int r = i - NOCC, r2 = j - NOCC;
    v = 0.5*((double)Fhh[r*NHID + r2] - (double)Fhh[r2*NHID + r]);
  }
  A[(size_t)i*PF_N + j] = v;
}

// ---- panel diag factorization: ONE block, 64x64, 2x2 pivots ----
// hist layout (doubles): [0..32) invt; [32..2080) sA=colA*invt (j*64+c);
//                        [2080..4128) sB=colB*invt.
__global__ __launch_bounds__(256) void k_panelD(const double* __restrict__ A,
      double* __restrict__ hist, double* __restrict__ lacc,
      int* __restrict__ nneg, int k){
  const int N = PF_N, c0 = 64*k;
  const int w  = (N - c0 < 64) ? (N - c0) : 64;
  const int np = w >> 1;
  const int tid = threadIdx.x;
  const int ty = tid >> 4, tx = tid & 15;
  __shared__ double colA[2][64], colB[2][64];
  __shared__ double sInv[32], sTv[32];
  __shared__ double sA[32][64], sB[32][64];
  double T4[4][4];
  #pragma unroll
  for (int q = 0; q < 4; q++)
    #pragma unroll
    for (int p = 0; p < 4; p++){
      int r = 4*ty+q, c = 4*tx+p;
      double v = 0.0;
      if (r < w && c < w){
        if (r > c) v = A[(size_t)(c0+r)*N + c0 + c];
        else if (r < c) v = -A[(size_t)(c0+c)*N + c0 + r];
      }
      T4[q][p] = v;
    }
  if (tx == 0){
    #pragma unroll
    for (int q = 0; q < 4; q++){
      colA[0][4*ty+q] = T4[q][0];
      colB[0][4*ty+q] = T4[q][1];
    }
  }
  if (tid == 0){ double t0 = T4[0][1]; sTv[0] = t0; sInv[0] = 1.0/t0; }
  __syncthreads();
  for (int j = 0; j < np; j++){
    const int pb = j & 1, nb = pb ^ 1;
    const double invt = sInv[j];
    if (tid < 64){
      sA[j][tid] = colA[pb][tid]*invt;
      sB[j][tid] = colB[pb][tid]*invt;
    }
    const int r2 = 2*j + 2;
    const bool pub = (j+1 < np) && (tx == (r2 >> 2));
    const int p0 = r2 & 3;
    #pragma unroll
    for (int q = 0; q < 4; q++){
      const int r = 4*ty + q;
      if (r >= r2){
        const double ar = colA[pb][r], br = colB[pb][r];
        #pragma unroll
        for (int p = 0; p < 4; p++){
          const int c = 4*tx + p;
          if (c >= r2) T4[q][p] += (br*colA[pb][c] - ar*colB[pb][c]) * invt;
        }
      }
      if (pub){ colA[nb][r] = T4[q][p0]; colB[nb][r] = T4[q][p0+1]; }
    }
    if (j+1 < np && ty == (r2 >> 2) && tx == (r2 >> 2)){
      const double t = T4[r2 & 3][(r2+1) & 3];
      sTv[j+1] = t; sInv[j+1] = 1.0/t;
    }
    __syncthreads();
  }
  // store history (only meaningful when np==32, i.e. R/T follow)
  if (tid < np) hist[tid] = sInv[tid];
  for (int idx = tid; idx < np*64; idx += 256){
    hist[32 + idx]        = sA[idx >> 6][idx & 63];
    hist[32 + 2048 + idx] = sB[idx >> 6][idx & 63];
  }
  // log/sign partial
  if (tid < 64){
    double lv = 0.0; int sg = 0;
    if (tid < np){ double t = sTv[tid]; lv = log(fabs(t)); sg = (t < 0.0) ? 1 : 0; }
    for (int o = 32; o > 0; o >>= 1){
      lv += __shfl_down(lv, o, 64);
      sg += __shfl_down(sg, o, 64);
    }
    if (tid == 0){ atomicAdd(lacc, lv); atomicAdd(nneg, sg); }
  }
}

// ---- panel-column update for trailing rows: one wave per row ----
__global__ __launch_bounds__(256) void k_panelR(double* __restrict__ A,
      const double* __restrict__ hist, int k){
  const int N = PF_N, c0 = 64*k, tc0 = c0 + 64;
  const int wv = threadIdx.x >> 6, lc = threadIdx.x & 63;
  const int i = tc0 + blockIdx.x*4 + wv;
  if (i >= N) return;
  double v = A[(size_t)i*N + c0 + lc];
  const double* hA = hist + 32;
  const double* hB = hist + 32 + 2048;
  #pragma unroll 8
  for (int j = 0; j < 32; j++){
    double a = __shfl(v, 2*j,   64);
    double b = __shfl(v, 2*j+1, 64);
    if (lc >= 2*j+2) v += b*hA[j*64+lc] - a*hB[j*64+lc];
  }
  A[(size_t)i*N + c0 + lc] = v;
}

// ---- trailing rank-64 Schur update: 64x64 lower-triangle tiles ----
__global__ __launch_bounds__(256) void k_trail(double* __restrict__ A,
      const double* __restrict__ hist, int k){
  const int N = PF_N, c0 = 64*k, tc0 = c0 + 64;
  const int tid = threadIdx.x;
  int I = 0, item = blockIdx.x;
  while ((I+1)*(I+2)/2 <= item) I++;
  const int J = item - I*(I+1)/2;
  const int i0 = tc0 + I*64, j0 = tc0 + J*64;
  const int iend = (i0 + 64 < N) ? (i0 + 64) : N;
  const int jend = (j0 + 64 < N) ? (j0 + 64) : N;
  __shared__ double sPiA[16][66], sPiB[16][66];
  __shared__ double sPjA[16][66], sPjB[16][66];
  __shared__ double sInvL[32];
  if (tid < 32) sInvL[tid] = hist[tid];
  const int ty = tid >> 4, tx = tid & 15;
  double acc[4][4];
  #pragma unroll
  for (int rr = 0; rr < 4; rr++)
    #pragma unroll
    for (int cc = 0; cc < 4; cc++){
      const int i = i0 + ty + 16*rr, j = j0 + tx + 16*cc;
      acc[rr][cc] = (i < iend && j < jend && i > j) ? A[(size_t)i*N + j] : 0.0;
    }
  __syncthreads();
  #pragma unroll
  for (int lh = 0; lh < 2; lh++){
    #pragma unroll
    for (int u = 0; u < 4; u++){
      const int idx = tid + u*256;
      const int r = idx >> 4, ll = idx & 15;
      const int l = lh*16 + ll;
      const double it = sInvL[l];
      const int gi = i0 + r;
      double a = 0.0, b = 0.0;
      if (gi < iend){
        a = A[(size_t)gi*N + c0 + 2*l];
        b = A[(size_t)gi*N + c0 + 2*l + 1];
      }
      sPiA[ll][r] = a; sPiB[ll][r] = b;
      const int gj = j0 + r;
      double a2 = 0.0, b2 = 0.0;
      if (gj < jend){
        a2 = A[(size_t)gj*N + c0 + 2*l];
        b2 = A[(size_t)gj*N + c0 + 2*l + 1];
      }
      sPjA[ll][r] = a2*it; sPjB[ll][r] = b2*it;
    }
    __syncthreads();
    #pragma unroll 4
    for (int ll = 0; ll < 16; ll++){
      double ar[4], br[4], ac[4], bc[4];
      #pragma unroll
      for (int rr = 0; rr < 4; rr++){
        ar[rr] = sPiA[ll][ty + 16*rr];
        br[rr] = sPiB[ll][ty + 16*rr];
      }
      #pragma unroll
      for (int cc = 0; cc < 4; cc++){
        ac[cc] = sPjA[ll][tx + 16*cc];
        bc[cc] = sPjB[ll][tx + 16*cc];
      }
      #pragma unroll
      for (int rr = 0; rr < 4; rr++)
        #pragma unroll
        for (int cc = 0; cc < 4; cc++)
          acc[rr][cc] += br[rr]*ac[cc] - ar[rr]*bc[cc];
    }
    __syncthreads();
  }
  #pragma unroll
  for (int rr = 0; rr < 4; rr++)
    #pragma unroll
    for (int cc = 0; cc < 4; cc++){
      const int i = i0 + ty + 16*rr, j = j0 + tx + 16*cc;
      if (i < iend && j < jend && i > j) A[(size_t)i*N + j] = acc[rr][cc];
    }
}

// ---- final output ----
__global__ void k_out(const double* __restrict__ lacc, const int* __restrict__ nneg,
                      const double* __restrict__ logJ, float* __restrict__ outp){
  if (threadIdx.x == 0){
    outp[0] = (*nneg & 1) ? -1.0f : 1.0f;
    outp[1] = (float)(*lacc + *logJ);
  }
}

// ---------------------------------------------------------------------------
extern "C" void kernel_launch(void* const* d_in, const int* in_sizes, int n_in,
                              void* d_out, int out_size, void* d_ws, size_t ws_size,
                              hipStream_t stream){
  (void)in_sizes; (void)n_in; (void)out_size; (void)ws_size;
  const float* x   = (const float*)d_in[0];
  const float* Fvv = (const float*)d_in[1];
  const float* Fhh = (const float*)d_in[2];
  const float* w1[4] = {(const float*)d_in[3], (const float*)d_in[7],
                        (const float*)d_in[11], (const float*)d_in[15]};
  const float* b1[4] = {(const float*)d_in[4], (const float*)d_in[8],
                        (const float*)d_in[12], (const float*)d_in[16]};
  const float* w2[4] = {(const float*)d_in[5], (const float*)d_in[9],
                        (const float*)d_in[13], (const float*)d_in[17]};
  const float* b2[3] = {(const float*)d_in[6], (const float*)d_in[10],
                        (const float*)d_in[14]};

  char* ws = (char*)d_ws;
  double* lacc  = (double*)(ws + 0);
  int*    nneg  = (int*)(ws + 8);
  double* logJa = (double*)(ws + 1024);
  int*    nidx  = (int*)(ws + 1088);
  double* hist  = (double*)(ws + 8192);         // 33 KB
  const size_t CB = 589824;  // 64*2304*4
  float* tbuf  = (float*)(ws + 49152);
  float* ybuf  = (float*)(ws + 49152 + CB);
  float* hbuf0 = (float*)(ws + 49152 + 2*CB);
  float* hbuf1 = (float*)(ws + 49152 + 3*CB);
  double* A    = (double*)(ws + 49152 + 4*CB);  // 2,408,448; 8.79 MB

  hipMemsetAsync(d_ws, 0, 2048, stream);        // lacc + nneg + logJ acc
  k_find_n<<<1,256,0,stream>>>(x, nidx);

  // CNN block 0: t = (h/sqrt(1))/sqrt(2); res repeats 2ch -> 64ch
  k_pre <<<18, 256,0,stream>>>(x, tbuf, 4608, 0, 0.70710678118654752f);
  k_conv<<<576,256,0,stream>>>(tbuf, w1[0], b1[0], nullptr, ybuf, 2, 0, 1, 1.0f);
  k_conv<<<576,256,0,stream>>>(ybuf, w2[0], b2[0], x,      hbuf0, 64, 2, 0, 1.0f);
  // block 1
  k_pre <<<576,256,0,stream>>>(hbuf0, tbuf, 147456, 1, 0.70710678118654752f);
  k_conv<<<576,256,0,stream>>>(tbuf, w1[1], b1[1], nullptr, ybuf, 64, 0, 1, 1.0f);
  k_conv<<<576,256,0,stream>>>(ybuf, w2[1], b2[1], hbuf0,  hbuf1, 64, 1, 0, 1.0f);
  // block 2
  k_pre <<<576,256,0,stream>>>(hbuf1, tbuf, 147456, 1, 0.57735026918962576f);
  k_conv<<<576,256,0,stream>>>(tbuf, w1[2], b1[2], nullptr, ybuf, 64, 0, 1, 1.0f);
  k_conv<<<576,256,0,stream>>>(ybuf, w2[2], b2[2], hbuf1,  hbuf0, 64, 1, 0, 1.0f);
  // block 3 (no b2; fold final 1/sqrt(5) into epilogue)
  k_pre <<<576,256,0,stream>>>(hbuf0, tbuf, 147456, 1, 0.5f);
  k_conv<<<576,256,0,stream>>>(tbuf, w1[3], b1[3], nullptr, ybuf, 64, 0, 1, 1.0f);
  k_conv<<<576,256,0,stream>>>(ybuf, w2[3], nullptr, hbuf0, hbuf1, 64, 1, 0,
                               0.44721359549995794f);

  k_logJ  <<<144,256,0,stream>>>(hbuf1, logJa);
  k_buildA<<<(PF_N*PF_N+255)/256,256,0,stream>>>(Fvv, Fhh, hbuf1, nidx, A);

  for (int k = 0; k < 17; k++){
    k_panelD<<<1,256,0,stream>>>(A, hist, lacc, nneg, k);
    const int m = PF_N - 64*(k+1);
    if (m > 0){
      k_panelR<<<(m+3)/4,256,0,stream>>>(A, hist, k);
      const int nt = (m + 63) >> 6;
      k_trail<<<nt*(nt+1)/2,256,0,stream>>>(A, hist, k);
    }
  }
  k_out<<<1,64,0,stream>>>(lacc, nneg, logJa, (float*)d_out);
}

// Round 10
// 1128.467 us; speedup vs baseline: 1.6132x; 1.6132x over previous
//
#include <hip/hip_runtime.h>
#include <math.h>

// ---------------------------------------------------------------------------
// HFPS: CNN (4 residual blocks, circular 3x3 conv, 48x48, 64ch) ->
//       A = [[Fvv[n][:,n], Fvh_n],[-Fvh_n^T, Fhh_a]] (1048x1048 skew) ->
//       sign(Pf(A)), log|Pf(A)| + log_J
// Pfaffian via unpivoted blocked skew LDL^T with 2x2 pivots, fp64.
//   Pf = prod(t_p); log|Pf| = sum log|t_p| = 0.5*slogdet(A).
//
// R10 (R9 post-mortem: k_panelD = 70 us x17 = 65% of runtime -- the serial
// diag factorization was the invariant pinning R5-R8 at ~1.1-1.26 ms):
//   - factor_lds: lower-triangle-only 2x2-pivot factorization, 256 threads
//     (4 col-quarters per row), broadcast LDS reads, ~6-10k cycles total
//     (vs ~170k for the old register-tile + 32 full-tile barrier steps).
//   - embedded in k_trail: tile (0,0)'s block overlays its just-computed
//     next-diag tile into LDS and factors it at the end of trail(k),
//     writing hist for panel k+1 (double-buffered). D leaves the critical
//     path; 17 k_panelD dispatches deleted (standalone fast k_panelD0 only
//     for tile 0).
//
// Workspace layout:
//   0: lacc (double)  8: nneg (int)  1024: logJ acc  1088: nidx[1024]
//   8192:  hist0 (4128 doubles = 33 KB)   41216: hist1
//   74240: tbuf/ybuf/hbuf0/hbuf1 (4 x 64*2304 fp32)  [CNN]
//   2433536: A (1048*1048 fp64 = 8.79 MB)  -> total ~11.2 MB
// ---------------------------------------------------------------------------

#define NPIX 2304          // 48*48
#define MSZ  4608          // 2*48*48
#define NOCC 1024
#define NHID 24
#define PF_N 1048          // NOCC + 2*NHID

__device__ __forceinline__ float gelu_f(float v){
  // jax.nn.gelu approximate=True (tanh form)
  float v3 = v*v*v;
  return 0.5f*v*(1.0f + tanhf(0.7978845608028654f*(v + 0.044715f*v3)));
}

// ---- occupied-site indices (sorted), x[i]==1.0f exactly ----
__global__ void k_find_n(const float* __restrict__ x, int* __restrict__ nidx){
  __shared__ int cnt[256];
  __shared__ int off[256];
  int t = threadIdx.x;
  int c = 0;
  for (int k = 0; k < 18; k++) c += (x[t*18+k] == 1.0f) ? 1 : 0;
  cnt[t] = c;
  __syncthreads();
  if (t == 0){ int s = 0; for (int q=0;q<256;q++){ off[q]=s; s+=cnt[q]; } }
  __syncthreads();
  int o = off[t];
  for (int k = 0; k < 18; k++){
    int idx = t*18+k;
    if (x[idx] == 1.0f) nidx[o++] = idx;
  }
}

// ---- elementwise pre-op: t = [gelu](h*scale) ----
__global__ void k_pre(const float* __restrict__ in, float* __restrict__ outp,
                      int count, int dogelu, float scale){
  int g = blockIdx.x*256 + threadIdx.x;
  if (g >= count) return;
  float v = in[g]*scale;
  if (dogelu) v = gelu_f(v);
  outp[g] = v;
}

// ---- circular 3x3 conv, 64 out channels, fused bias/gelu/residual/scale ----
__global__ __launch_bounds__(256) void k_conv(const float* __restrict__ in,
      const float* __restrict__ wgt, const float* __restrict__ bias,
      const float* __restrict__ res, float* __restrict__ outp,
      int cin, int resmode, int dogelu, float scale){
  int c = blockIdx.x / 9;
  int p = (blockIdx.x % 9)*256 + threadIdx.x;
  int y = p / 48, x = p - y*48;
  int ym = ((y+47)%48)*48, y0 = y*48, yp = ((y+1)%48)*48;
  int xm = (x+47)%48, xq = (x+1)%48;
  float s = 0.f;
  const float* wp = wgt + c*cin*9;
  for (int ci = 0; ci < cin; ci++){
    const float* b_ = in + ci*NPIX;
    s += b_[ym+xm]*wp[0] + b_[ym+x]*wp[1] + b_[ym+xq]*wp[2]
       + b_[y0+xm]*wp[3] + b_[y0+x]*wp[4] + b_[y0+xq]*wp[5]
       + b_[yp+xm]*wp[6] + b_[yp+x]*wp[7] + b_[yp+xq]*wp[8];
    wp += 9;
  }
  if (bias) s += bias[c];
  if (dogelu) s = gelu_f(s);
  if (resmode == 1) s += res[c*NPIX + p];
  else if (resmode == 2) s += res[(c>>5)*NPIX + p];  // jnp.repeat(res,32,axis=0)
  s *= scale;
  outp[c*NPIX + p] = s;
}

// ---- log_J = sum over channels 48..63 of final h ----
__global__ void k_logJ(const float* __restrict__ hfin, double* __restrict__ acc){
  int g = blockIdx.x*256 + threadIdx.x;   // 144*256 = 36864
  double v = (double)hfin[48*NPIX + g];
  for (int o = 32; o > 0; o >>= 1) v += __shfl_down(v, o, 64);
  __shared__ double wsum[4];
  int lane = threadIdx.x & 63, wv = threadIdx.x >> 6;
  if (lane == 0) wsum[wv] = v;
  __syncthreads();
  if (threadIdx.x == 0) atomicAdd(acc, wsum[0]+wsum[1]+wsum[2]+wsum[3]);
}

// F_vh[m][r] = out[2r + (m>=2304)][m % 2304]
__device__ __forceinline__ double fvh_val(const float* h, int m, int r){
  int s = (m >= NPIX) ? 1 : 0;
  int p = m - s*NPIX;
  return (double)h[(2*r+s)*NPIX + p];
}

// ---- assemble skew matrix A, LOWER TRIANGLE ONLY (upper never read) ----
__global__ void k_buildA(const float* __restrict__ Fvv, const float* __restrict__ Fhh,
                         const float* __restrict__ hfin, const int* __restrict__ nidx,
                         double* __restrict__ A){
  int g = blockIdx.x*256 + threadIdx.x;
  if (g >= PF_N*PF_N) return;
  int i = g / PF_N, j = g - i*PF_N;
  if (j >= i) return;
  double v;
  if (i < NOCC){
    int ni = nidx[i], nj = nidx[j];
    v = 0.5*((double)Fvv[(size_t)ni*MSZ + nj] - (double)Fvv[(size_t)nj*MSZ + ni]);
  } else if (j < NOCC){
    v = -fvh_val(hfin, nidx[j], i - NOCC);
  } else {
    int r = i - NOCC, r2 = j - NOCC;
    v = 0.5*((double)Fhh[r*NHID + r2] - (double)Fhh[r2*NHID + r]);
  }
  A[(size_t)i*PF_N + j] = v;
}

// ---- fast lower-triangle 2x2-pivot factorization of a diag tile in LDS ----
// D: [w][stride 65], lower entries (r>c) = A values. 256 threads:
// thread (r = tid&63, qu = tid>>6) updates quarter qu of row r's cols.
// Per step j (pivot rows r0=2j, r1=2j+1, t = A[r0][r1] = -D[r1][r0]):
//   D[r][c] += (b_r*a_c - a_r*b_c)/t for r,c >= 2j+2, c < r
//   with a_x = D[x][r0], b_x = D[x][r1] (lower: x > r1).
// hist layout: [0..32) invt; [32..2080) a_c*invt; [2080..4128) b_c*invt.
__device__ __forceinline__ void factor_lds(double* D, double* sTf, int w,
      double* __restrict__ histN, double* __restrict__ lacc,
      int* __restrict__ nneg){
  const int tid = threadIdx.x;
  const int r = tid & 63, qu = tid >> 6;
  const int np = w >> 1;
  for (int j = 0; j < np; j++){
    const int r0 = 2*j, r1 = r0 + 1;
    const double t = -D[r1*65 + r0];
    const double invt = 1.0 / t;
    if (tid == 0) sTf[j] = t;
    const bool rowok = (r < w) && (r >= r0 + 2);
    if (rowok){
      const double ar = D[r*65 + r0], br = D[r*65 + r1];
      if (qu == 0){
        histN[32 + j*64 + r]        = ar * invt;
        histN[32 + 2048 + j*64 + r] = br * invt;
      }
      const int lo = r0 + 2, hi = r;
      const int per = (hi - lo + 3) >> 2;
      const int cb = lo + qu*per;
      int ce = cb + per; if (ce > hi) ce = hi;
      for (int c = cb; c < ce; c++){
        const double ac = D[c*65 + r0], bc = D[c*65 + r1];
        D[r*65 + c] += (br*ac - ar*bc) * invt;
      }
    }
    __syncthreads();
  }
  if (tid < np) histN[tid] = 1.0 / sTf[tid];
  if (tid < 64){
    double lv = 0.0; int sg = 0;
    if (tid < np){ double t = sTf[tid]; lv = log(fabs(t)); sg = (t < 0.0) ? 1 : 0; }
    for (int o = 32; o > 0; o >>= 1){
      lv += __shfl_down(lv, o, 64);
      sg += __shfl_down(sg, o, 64);
    }
    if (tid == 0){ atomicAdd(lacc, lv); atomicAdd(nneg, sg); }
  }
}

// ---- standalone factor of tile 0 ----
__global__ __launch_bounds__(256) void k_panelD0(const double* __restrict__ A,
      double* __restrict__ hist, double* __restrict__ lacc,
      int* __restrict__ nneg){
  __shared__ double D[64*65];
  __shared__ double sTf[32];
  const int tid = threadIdx.x;
  for (int idx = tid; idx < 64*64; idx += 256){
    int r = idx >> 6, c = idx & 63;
    if (r > c) D[r*65+c] = A[(size_t)r*PF_N + c];
  }
  __syncthreads();
  factor_lds(D, sTf, 64, hist, lacc, nneg);
}

// ---- panel-column update for trailing rows: one wave per row ----
__global__ __launch_bounds__(256) void k_panelR(double* __restrict__ A,
      const double* __restrict__ hist, int k){
  const int N = PF_N, c0 = 64*k, tc0 = c0 + 64;
  const int wv = threadIdx.x >> 6, lc = threadIdx.x & 63;
  const int i = tc0 + blockIdx.x*4 + wv;
  if (i >= N) return;
  double v = A[(size_t)i*N + c0 + lc];
  const double* hA = hist + 32;
  const double* hB = hist + 32 + 2048;
  #pragma unroll 8
  for (int j = 0; j < 32; j++){
    double a = __shfl(v, 2*j,   64);
    double b = __shfl(v, 2*j+1, 64);
    if (lc >= 2*j+2) v += b*hA[j*64+lc] - a*hB[j*64+lc];
  }
  A[(size_t)i*N + c0 + lc] = v;
}

// ---- trailing rank-64 Schur update (64x64 lower-triangle tiles) + embedded
//      factorization of the NEXT diag tile by the (0,0)-tile block ----
__global__ __launch_bounds__(256) void k_trail(double* __restrict__ A,
      const double* __restrict__ histR, double* __restrict__ histW,
      double* __restrict__ lacc, int* __restrict__ nneg, int k){
  const int N = PF_N, c0 = 64*k, tc0 = c0 + 64;
  const int tid = threadIdx.x;
  int I = 0, item = blockIdx.x;
  while ((I+1)*(I+2)/2 <= item) I++;
  const int J = item - I*(I+1)/2;
  const int i0 = tc0 + I*64, j0 = tc0 + J*64;
  const int iend = (i0 + 64 < N) ? (i0 + 64) : N;
  const int jend = (j0 + 64 < N) ? (j0 + 64) : N;
  __shared__ double shmem[4224];    // staging [4][16][66] OR D[64][65]
  __shared__ double sInvL[32];
  __shared__ double sTf[32];
  double* sPiA = shmem;
  double* sPiB = shmem + 1056;
  double* sPjA = shmem + 2112;
  double* sPjB = shmem + 3168;
  if (tid < 32) sInvL[tid] = histR[tid];
  const int ty = tid >> 4, tx = tid & 15;
  double acc[4][4];
  #pragma unroll
  for (int rr = 0; rr < 4; rr++)
    #pragma unroll
    for (int cc = 0; cc < 4; cc++){
      const int i = i0 + ty + 16*rr, j = j0 + tx + 16*cc;
      acc[rr][cc] = (i < iend && j < jend && i > j) ? A[(size_t)i*N + j] : 0.0;
    }
  __syncthreads();
  #pragma unroll
  for (int lh = 0; lh < 2; lh++){
    #pragma unroll
    for (int u = 0; u < 4; u++){
      const int idx = tid + u*256;
      const int r = idx >> 4, ll = idx & 15;
      const int l = lh*16 + ll;
      const double it = sInvL[l];
      const int gi = i0 + r;
      double a = 0.0, b = 0.0;
      if (gi < iend){
        a = A[(size_t)gi*N + c0 + 2*l];
        b = A[(size_t)gi*N + c0 + 2*l + 1];
      }
      sPiA[ll*66+r] = a; sPiB[ll*66+r] = b;
      const int gj = j0 + r;
      double a2 = 0.0, b2 = 0.0;
      if (gj < jend){
        a2 = A[(size_t)gj*N + c0 + 2*l];
        b2 = A[(size_t)gj*N + c0 + 2*l + 1];
      }
      sPjA[ll*66+r] = a2*it; sPjB[ll*66+r] = b2*it;
    }
    __syncthreads();
    #pragma unroll 4
    for (int ll = 0; ll < 16; ll++){
      double ar[4], br[4], ac[4], bc[4];
      #pragma unroll
      for (int rr = 0; rr < 4; rr++){
        ar[rr] = sPiA[ll*66 + ty + 16*rr];
        br[rr] = sPiB[ll*66 + ty + 16*rr];
      }
      #pragma unroll
      for (int cc = 0; cc < 4; cc++){
        ac[cc] = sPjA[ll*66 + tx + 16*cc];
        bc[cc] = sPjB[ll*66 + tx + 16*cc];
      }
      #pragma unroll
      for (int rr = 0; rr < 4; rr++)
        #pragma unroll
        for (int cc = 0; cc < 4; cc++)
          acc[rr][cc] += br[rr]*ac[cc] - ar[rr]*bc[cc];
    }
    __syncthreads();
  }
  #pragma unroll
  for (int rr = 0; rr < 4; rr++)
    #pragma unroll
    for (int cc = 0; cc < 4; cc++){
      const int i = i0 + ty + 16*rr, j = j0 + tx + 16*cc;
      if (i < iend && j < jend && i > j) A[(size_t)i*N + j] = acc[rr][cc];
    }
  // ---- embedded factorization of the next diag tile (block 0 only) ----
  if (blockIdx.x == 0){
    __syncthreads();
    const int wn = iend - i0;            // next diag width (64 or tail 24)
    #pragma unroll
    for (int rr = 0; rr < 4; rr++)
      #pragma unroll
      for (int cc = 0; cc < 4; cc++){
        const int i = i0 + ty + 16*rr, j = j0 + tx + 16*cc;
        if (i < iend && j < jend && i > j)
          shmem[(i - i0)*65 + (j - j0)] = acc[rr][cc];
      }
    __syncthreads();
    factor_lds(shmem, sTf, wn, histW, lacc, nneg);
  }
}

// ---- final output ----
__global__ void k_out(const double* __restrict__ lacc, const int* __restrict__ nneg,
                      const double* __restrict__ logJ, float* __restrict__ outp){
  if (threadIdx.x == 0){
    outp[0] = (*nneg & 1) ? -1.0f : 1.0f;
    outp[1] = (float)(*lacc + *logJ);
  }
}

// ---------------------------------------------------------------------------
extern "C" void kernel_launch(void* const* d_in, const int* in_sizes, int n_in,
                              void* d_out, int out_size, void* d_ws, size_t ws_size,
                              hipStream_t stream){
  (void)in_sizes; (void)n_in; (void)out_size; (void)ws_size;
  const float* x   = (const float*)d_in[0];
  const float* Fvv = (const float*)d_in[1];
  const float* Fhh = (const float*)d_in[2];
  const float* w1[4] = {(const float*)d_in[3], (const float*)d_in[7],
                        (const float*)d_in[11], (const float*)d_in[15]};
  const float* b1[4] = {(const float*)d_in[4], (const float*)d_in[8],
                        (const float*)d_in[12], (const float*)d_in[16]};
  const float* w2[4] = {(const float*)d_in[5], (const float*)d_in[9],
                        (const float*)d_in[13], (const float*)d_in[17]};
  const float* b2[3] = {(const float*)d_in[6], (const float*)d_in[10],
                        (const float*)d_in[14]};

  char* ws = (char*)d_ws;
  double* lacc  = (double*)(ws + 0);
  int*    nneg  = (int*)(ws + 8);
  double* logJa = (double*)(ws + 1024);
  int*    nidx  = (int*)(ws + 1088);
  double* hist0 = (double*)(ws + 8192);         // 33 KB
  double* hist1 = (double*)(ws + 41216);        // 33 KB
  const size_t CB = 589824;  // 64*2304*4
  float* tbuf  = (float*)(ws + 74240);
  float* ybuf  = (float*)(ws + 74240 + CB);
  float* hbuf0 = (float*)(ws + 74240 + 2*CB);
  float* hbuf1 = (float*)(ws + 74240 + 3*CB);
  double* A    = (double*)(ws + 74240 + 4*CB);  // 2,433,536; 8.79 MB

  hipMemsetAsync(d_ws, 0, 2048, stream);        // lacc + nneg + logJ acc
  k_find_n<<<1,256,0,stream>>>(x, nidx);

  // CNN block 0: t = (h/sqrt(1))/sqrt(2); res repeats 2ch -> 64ch
  k_pre <<<18, 256,0,stream>>>(x, tbuf, 4608, 0, 0.70710678118654752f);
  k_conv<<<576,256,0,stream>>>(tbuf, w1[0], b1[0], nullptr, ybuf, 2, 0, 1, 1.0f);
  k_conv<<<576,256,0,stream>>>(ybuf, w2[0], b2[0], x,      hbuf0, 64, 2, 0, 1.0f);
  // block 1
  k_pre <<<576,256,0,stream>>>(hbuf0, tbuf, 147456, 1, 0.70710678118654752f);
  k_conv<<<576,256,0,stream>>>(tbuf, w1[1], b1[1], nullptr, ybuf, 64, 0, 1, 1.0f);
  k_conv<<<576,256,0,stream>>>(ybuf, w2[1], b2[1], hbuf0,  hbuf1, 64, 1, 0, 1.0f);
  // block 2
  k_pre <<<576,256,0,stream>>>(hbuf1, tbuf, 147456, 1, 0.57735026918962576f);
  k_conv<<<576,256,0,stream>>>(tbuf, w1[2], b1[2], nullptr, ybuf, 64, 0, 1, 1.0f);
  k_conv<<<576,256,0,stream>>>(ybuf, w2[2], b2[2], hbuf1,  hbuf0, 64, 1, 0, 1.0f);
  // block 3 (no b2; fold final 1/sqrt(5) into epilogue)
  k_pre <<<576,256,0,stream>>>(hbuf0, tbuf, 147456, 1, 0.5f);
  k_conv<<<576,256,0,stream>>>(tbuf, w1[3], b1[3], nullptr, ybuf, 64, 0, 1, 1.0f);
  k_conv<<<576,256,0,stream>>>(ybuf, w2[3], nullptr, hbuf0, hbuf1, 64, 1, 0,
                               0.44721359549995794f);

  k_logJ  <<<144,256,0,stream>>>(hbuf1, logJa);
  k_buildA<<<(PF_N*PF_N+255)/256,256,0,stream>>>(Fvv, Fhh, hbuf1, nidx, A);

  k_panelD0<<<1,256,0,stream>>>(A, hist0, lacc, nneg);
  for (int k = 0; k < 16; k++){
    double* hR = (k & 1) ? hist1 : hist0;
    double* hW = (k & 1) ? hist0 : hist1;
    const int m = PF_N - 64*(k+1);
    k_panelR<<<(m+3)/4,256,0,stream>>>(A, hR, k);
    const int nt = (m + 63) >> 6;
    k_trail<<<nt*(nt+1)/2,256,0,stream>>>(A, hR, hW, lacc, nneg, k);
  }
  k_out<<<1,64,0,stream>>>(lacc, nneg, logJa, (float*)d_out);
}

// Round 11
// 1120.726 us; speedup vs baseline: 1.6243x; 1.0069x over previous
//
#include <hip/hip_runtime.h>
#include <math.h>

// ---------------------------------------------------------------------------
// HFPS: CNN (4 residual blocks, circular 3x3 conv, 48x48, 64ch) ->
//       A = [[Fvv[n][:,n], Fvh_n],[-Fvh_n^T, Fhh_a]] (1048x1048 skew) ->
//       sign(Pf(A)), log|Pf(A)| + log_J
// Pfaffian via unpivoted blocked skew LDL^T with 2x2 pivots, fp64.
//   Pf = prod(t_p); log|Pf| = sum log|t_p| = 0.5*slogdet(A).
//
// R11 (R10 post-mortem: fast embedded D WIN 1820->1128; every kernel now
// <51 us; remaining time = ~50 serial dispatches + per-kernel latency):
//   - k_conv: 3px/thread register blocking (15 loads / 27 MAC vs 27/27);
//     fused pre-gelu epilogue (k_pre x3 deleted) and fused logJ reduction
//     (k_logJ deleted). 384 blocks x 128 thr.
//   - k_buildAvv: 32x32 LDS tile transpose -> both Fvv gathers coalesced
//     (old transposed gather touched 64 lines/wave); k_buildAs for the 24
//     hidden-row strips.
//   - k_out folded into trail(15) block 0 (atomicAdd return values).
//   - k_find_n merged into k_prep (also writes block-0 pre).
//   Pfaffian R/trail/embedded-D structure unchanged (proven R10).
//
// Workspace layout:
//   0: lacc (double)  8: nneg (int)  1024: logJ acc  1088: nidx[1024]
//   8192:  hist0 (4128 doubles = 33 KB)   41216: hist1
//   74240: tbuf/ybuf/hbuf0/hbuf1 (4 x 64*2304 fp32)  [CNN]
//   2433536: A (1048*1048 fp64 = 8.79 MB)  -> total ~11.2 MB
// ---------------------------------------------------------------------------

#define NPIX 2304          // 48*48
#define MSZ  4608          // 2*48*48
#define NOCC 1024
#define NHID 24
#define PF_N 1048          // NOCC + 2*NHID

__device__ __forceinline__ float gelu_f(float v){
  // jax.nn.gelu approximate=True (tanh form)
  float v3 = v*v*v;
  return 0.5f*v*(1.0f + tanhf(0.7978845608028654f*(v + 0.044715f*v3)));
}

// ---- occupied indices (sorted) + block-0 pre (t = x/sqrt(2)) ----
__global__ void k_prep(const float* __restrict__ x, int* __restrict__ nidx,
                       float* __restrict__ tbuf){
  __shared__ int cnt[256];
  __shared__ int off[256];
  int t = threadIdx.x;
  int c = 0;
  for (int k = 0; k < 18; k++){
    int idx = t*18 + k;
    float v = x[idx];
    c += (v == 1.0f) ? 1 : 0;
    tbuf[idx] = v * 0.70710678118654752f;
  }
  cnt[t] = c;
  __syncthreads();
  if (t == 0){ int s = 0; for (int q=0;q<256;q++){ off[q]=s; s+=cnt[q]; } }
  __syncthreads();
  int o = off[t];
  for (int k = 0; k < 18; k++){
    int idx = t*18+k;
    if (x[idx] == 1.0f) nidx[o++] = idx;
  }
}

// ---- circular 3x3 conv, 3 px/thread, fused bias/gelu/res/scale/pre/logJ ----
// grid = 64ch x 6 rowgroups = 384 blocks, 128 threads.
__global__ __launch_bounds__(128) void k_conv(const float* __restrict__ in,
      const float* __restrict__ wgt, const float* __restrict__ bias,
      const float* __restrict__ res, float* __restrict__ outp,
      float* __restrict__ pre_out, double* __restrict__ logJ_acc,
      int cin, int resmode, int dogelu, float scale, float pre_scale){
  const int c  = blockIdx.x / 6;
  const int rg = blockIdx.x % 6;
  const int tid = threadIdx.x;
  const int y  = rg*8 + (tid >> 4);
  const int xg = (tid & 15)*3;
  const int ym = ((y+47)%48)*48, y0 = y*48, yp = ((y+1)%48)*48;
  int c5[5];
  #pragma unroll
  for (int t = 0; t < 5; t++){
    int xx = xg - 1 + t;
    c5[t] = (xx < 0) ? 47 : ((xx >= 48) ? xx - 48 : xx);
  }
  float s0 = 0.f, s1 = 0.f, s2 = 0.f;
  const float* wp = wgt + c*cin*9;
  for (int ci = 0; ci < cin; ci++){
    const float* b_ = in + ci*NPIX;
    #pragma unroll
    for (int rr = 0; rr < 3; rr++){
      const int rb = (rr == 0) ? ym : ((rr == 1) ? y0 : yp);
      float v0 = b_[rb+c5[0]], v1 = b_[rb+c5[1]], v2 = b_[rb+c5[2]];
      float v3 = b_[rb+c5[3]], v4 = b_[rb+c5[4]];
      float w0 = wp[3*rr], w1 = wp[3*rr+1], w2 = wp[3*rr+2];
      s0 += v0*w0 + v1*w1 + v2*w2;
      s1 += v1*w0 + v2*w1 + v3*w2;
      s2 += v2*w0 + v3*w1 + v4*w2;
    }
    wp += 9;
  }
  const float bv = bias ? bias[c] : 0.f;
  const int base = c*NPIX + y0 + xg;
  float sv[3] = {s0, s1, s2};
  double ls = 0.0;
  #pragma unroll
  for (int t = 0; t < 3; t++){
    float s = sv[t] + bv;
    if (dogelu) s = gelu_f(s);
    if (resmode == 1) s += res[c*NPIX + y0 + xg + t];
    else if (resmode == 2) s += res[(c>>5)*NPIX + y0 + xg + t];
    s *= scale;
    outp[base+t] = s;
    if (pre_out) pre_out[base+t] = gelu_f(s * pre_scale);
    ls += (double)s;
  }
  if (logJ_acc && c >= 48){
    for (int o = 32; o > 0; o >>= 1) ls += __shfl_down(ls, o, 64);
    if ((tid & 63) == 0) atomicAdd(logJ_acc, ls);
  }
}

// ---- build A lower triangle, vv part: 32x32 LDS tile transpose ----
__global__ __launch_bounds__(256) void k_buildAvv(const float* __restrict__ Fvv,
      const int* __restrict__ nidx, double* __restrict__ A){
  __shared__ float G1[32][33], G2[32][33];
  __shared__ int sNi[32], sNj[32];
  int I = 0, item = blockIdx.x;          // 528 lower tiles of 1024/32
  while ((I+1)*(I+2)/2 <= item) I++;
  const int J = item - I*(I+1)/2;
  const int i0 = I*32, j0 = J*32;
  const int tid = threadIdx.x;
  if (tid < 32){ sNi[tid] = nidx[i0+tid]; }
  else if (tid < 64){ sNj[tid-32] = nidx[j0+tid-32]; }
  __syncthreads();
  for (int idx = tid; idx < 32*32; idx += 256){
    const int r = idx >> 5, c = idx & 31;
    G1[r][c] = Fvv[(size_t)sNi[r]*MSZ + sNj[c]];
    G2[r][c] = Fvv[(size_t)sNj[r]*MSZ + sNi[c]];
  }
  __syncthreads();
  for (int idx = tid; idx < 32*32; idx += 256){
    const int r = idx >> 5, c = idx & 31;
    const int i = i0 + r, j = j0 + c;
    if (i > j)
      A[(size_t)i*PF_N + j] = 0.5*((double)G1[r][c] - (double)G2[c][r]);
  }
}

// ---- build A strips: rows 1024..1047 (vh gather + hh) ----
__global__ void k_buildAs(const float* __restrict__ Fhh,
      const float* __restrict__ hfin, const int* __restrict__ nidx,
      double* __restrict__ A){
  int g = blockIdx.x*256 + threadIdx.x;
  if (g >= 24*PF_N) return;
  const int i = NOCC + g / PF_N, j = g % PF_N;
  if (j >= i) return;
  const int r = i - NOCC;
  double v;
  if (j < NOCC){
    int nj = nidx[j];
    int ss = (nj >= NPIX) ? 1 : 0;
    v = -(double)hfin[(2*r+ss)*NPIX + (nj - ss*NPIX)];
  } else {
    int r2 = j - NOCC;
    v = 0.5*((double)Fhh[r*NHID + r2] - (double)Fhh[r2*NHID + r]);
  }
  A[(size_t)i*PF_N + j] = v;
}

// ---- fast lower-triangle 2x2-pivot factorization of a diag tile in LDS ----
// D: [w][stride 65], lower entries (r>c). 256 threads; thread (r=tid&63,
// qu=tid>>6) updates quarter qu of row r. Results: histN + (lv,sg) on tid 0.
__device__ __forceinline__ void factor_lds(double* D, double* sTf, int w,
      double* __restrict__ histN, double& lv_out, int& sg_out){
  const int tid = threadIdx.x;
  const int r = tid & 63, qu = tid >> 6;
  const int np = w >> 1;
  for (int j = 0; j < np; j++){
    const int r0 = 2*j, r1 = r0 + 1;
    const double t = -D[r1*65 + r0];
    const double invt = 1.0 / t;
    if (tid == 0) sTf[j] = t;
    const bool rowok = (r < w) && (r >= r0 + 2);
    if (rowok){
      const double ar = D[r*65 + r0], br = D[r*65 + r1];
      if (qu == 0){
        histN[32 + j*64 + r]        = ar * invt;
        histN[32 + 2048 + j*64 + r] = br * invt;
      }
      const int lo = r0 + 2, hi = r;
      const int per = (hi - lo + 3) >> 2;
      const int cb = lo + qu*per;
      int ce = cb + per; if (ce > hi) ce = hi;
      for (int c = cb; c < ce; c++){
        const double ac = D[c*65 + r0], bc = D[c*65 + r1];
        D[r*65 + c] += (br*ac - ar*bc) * invt;
      }
    }
    __syncthreads();
  }
  if (tid < np) histN[tid] = 1.0 / sTf[tid];
  lv_out = 0.0; sg_out = 0;
  if (tid < 64){
    double lv = 0.0; int sg = 0;
    if (tid < np){ double t = sTf[tid]; lv = log(fabs(t)); sg = (t < 0.0) ? 1 : 0; }
    for (int o = 32; o > 0; o >>= 1){
      lv += __shfl_down(lv, o, 64);
      sg += __shfl_down(sg, o, 64);
    }
    if (tid == 0){ lv_out = lv; sg_out = sg; }
  }
}

// ---- standalone factor of tile 0 ----
__global__ __launch_bounds__(256) void k_panelD0(const double* __restrict__ A,
      double* __restrict__ hist, double* __restrict__ lacc,
      int* __restrict__ nneg){
  __shared__ double D[64*65];
  __shared__ double sTf[32];
  const int tid = threadIdx.x;
  for (int idx = tid; idx < 64*64; idx += 256){
    int r = idx >> 6, c = idx & 63;
    if (r > c) D[r*65+c] = A[(size_t)r*PF_N + c];
  }
  __syncthreads();
  double lv; int sg;
  factor_lds(D, sTf, 64, hist, lv, sg);
  if (tid == 0){ atomicAdd(lacc, lv); atomicAdd(nneg, sg); }
}

// ---- panel-column update for trailing rows: one wave per row ----
__global__ __launch_bounds__(256) void k_panelR(double* __restrict__ A,
      const double* __restrict__ hist, int k){
  const int N = PF_N, c0 = 64*k, tc0 = c0 + 64;
  const int wv = threadIdx.x >> 6, lc = threadIdx.x & 63;
  const int i = tc0 + blockIdx.x*4 + wv;
  if (i >= N) return;
  double v = A[(size_t)i*N + c0 + lc];
  const double* hA = hist + 32;
  const double* hB = hist + 32 + 2048;
  #pragma unroll 8
  for (int j = 0; j < 32; j++){
    double a = __shfl(v, 2*j,   64);
    double b = __shfl(v, 2*j+1, 64);
    if (lc >= 2*j+2) v += b*hA[j*64+lc] - a*hB[j*64+lc];
  }
  A[(size_t)i*N + c0 + lc] = v;
}

// ---- trailing rank-64 Schur update (64x64 lower-tri tiles) + embedded
//      factorization of the NEXT diag tile (block 0) + final output fold ----
__global__ __launch_bounds__(256) void k_trail(double* __restrict__ A,
      const double* __restrict__ histR, double* __restrict__ histW,
      double* __restrict__ lacc, int* __restrict__ nneg,
      const double* __restrict__ logJ, float* __restrict__ outp,
      int k, int fin){
  const int N = PF_N, c0 = 64*k, tc0 = c0 + 64;
  const int tid = threadIdx.x;
  int I = 0, item = blockIdx.x;
  while ((I+1)*(I+2)/2 <= item) I++;
  const int J = item - I*(I+1)/2;
  const int i0 = tc0 + I*64, j0 = tc0 + J*64;
  const int iend = (i0 + 64 < N) ? (i0 + 64) : N;
  const int jend = (j0 + 64 < N) ? (j0 + 64) : N;
  __shared__ double shmem[4224];    // staging [4][16][66] OR D[64][65]
  __shared__ double sInvL[32];
  __shared__ double sTf[32];
  double* sPiA = shmem;
  double* sPiB = shmem + 1056;
  double* sPjA = shmem + 2112;
  double* sPjB = shmem + 3168;
  if (tid < 32) sInvL[tid] = histR[tid];
  const int ty = tid >> 4, tx = tid & 15;
  double acc[4][4];
  #pragma unroll
  for (int rr = 0; rr < 4; rr++)
    #pragma unroll
    for (int cc = 0; cc < 4; cc++){
      const int i = i0 + ty + 16*rr, j = j0 + tx + 16*cc;
      acc[rr][cc] = (i < iend && j < jend && i > j) ? A[(size_t)i*N + j] : 0.0;
    }
  __syncthreads();
  #pragma unroll
  for (int lh = 0; lh < 2; lh++){
    #pragma unroll
    for (int u = 0; u < 4; u++){
      const int idx = tid + u*256;
      const int r = idx >> 4, ll = idx & 15;
      const int l = lh*16 + ll;
      const double it = sInvL[l];
      const int gi = i0 + r;
      double a = 0.0, b = 0.0;
      if (gi < iend){
        a = A[(size_t)gi*N + c0 + 2*l];
        b = A[(size_t)gi*N + c0 + 2*l + 1];
      }
      sPiA[ll*66+r] = a; sPiB[ll*66+r] = b;
      const int gj = j0 + r;
      double a2 = 0.0, b2 = 0.0;
      if (gj < jend){
        a2 = A[(size_t)gj*N + c0 + 2*l];
        b2 = A[(size_t)gj*N + c0 + 2*l + 1];
      }
      sPjA[ll*66+r] = a2*it; sPjB[ll*66+r] = b2*it;
    }
    __syncthreads();
    #pragma unroll 4
    for (int ll = 0; ll < 16; ll++){
      double ar[4], br[4], ac[4], bc[4];
      #pragma unroll
      for (int rr = 0; rr < 4; rr++){
        ar[rr] = sPiA[ll*66 + ty + 16*rr];
        br[rr] = sPiB[ll*66 + ty + 16*rr];
      }
      #pragma unroll
      for (int cc = 0; cc < 4; cc++){
        ac[cc] = sPjA[ll*66 + tx + 16*cc];
        bc[cc] = sPjB[ll*66 + tx + 16*cc];
      }
      #pragma unroll
      for (int rr = 0; rr < 4; rr++)
        #pragma unroll
        for (int cc = 0; cc < 4; cc++)
          acc[rr][cc] += br[rr]*ac[cc] - ar[rr]*bc[cc];
    }
    __syncthreads();
  }
  #pragma unroll
  for (int rr = 0; rr < 4; rr++)
    #pragma unroll
    for (int cc = 0; cc < 4; cc++){
      const int i = i0 + ty + 16*rr, j = j0 + tx + 16*cc;
      if (i < iend && j < jend && i > j) A[(size_t)i*N + j] = acc[rr][cc];
    }
  // ---- embedded factorization of the next diag tile (block 0 only) ----
  if (blockIdx.x == 0){
    __syncthreads();
    const int wn = iend - i0;            // next diag width (64 or tail 24)
    #pragma unroll
    for (int rr = 0; rr < 4; rr++)
      #pragma unroll
      for (int cc = 0; cc < 4; cc++){
        const int i = i0 + ty + 16*rr, j = j0 + tx + 16*cc;
        if (i < iend && j < jend && i > j)
          shmem[(i - i0)*65 + (j - j0)] = acc[rr][cc];
      }
    __syncthreads();
    double lv; int sg;
    factor_lds(shmem, sTf, wn, histW, lv, sg);
    if (tid == 0){
      double lold = atomicAdd(lacc, lv);
      int sold = atomicAdd(nneg, sg);
      if (fin){
        int stot = sold + sg;
        outp[0] = (stot & 1) ? -1.0f : 1.0f;
        outp[1] = (float)(lold + lv + logJ[0]);
      }
    }
  }
}

// ---------------------------------------------------------------------------
extern "C" void kernel_launch(void* const* d_in, const int* in_sizes, int n_in,
                              void* d_out, int out_size, void* d_ws, size_t ws_size,
                              hipStream_t stream){
  (void)in_sizes; (void)n_in; (void)out_size; (void)ws_size;
  const float* x   = (const float*)d_in[0];
  const float* Fvv = (const float*)d_in[1];
  const float* Fhh = (const float*)d_in[2];
  const float* w1[4] = {(const float*)d_in[3], (const float*)d_in[7],
                        (const float*)d_in[11], (const float*)d_in[15]};
  const float* b1[4] = {(const float*)d_in[4], (const float*)d_in[8],
                        (const float*)d_in[12], (const float*)d_in[16]};
  const float* w2[4] = {(const float*)d_in[5], (const float*)d_in[9],
                        (const float*)d_in[13], (const float*)d_in[17]};
  const float* b2[3] = {(const float*)d_in[6], (const float*)d_in[10],
                        (const float*)d_in[14]};

  char* ws = (char*)d_ws;
  double* lacc  = (double*)(ws + 0);
  int*    nneg  = (int*)(ws + 8);
  double* logJa = (double*)(ws + 1024);
  int*    nidx  = (int*)(ws + 1088);
  double* hist0 = (double*)(ws + 8192);         // 33 KB
  double* hist1 = (double*)(ws + 41216);        // 33 KB
  const size_t CB = 589824;  // 64*2304*4
  float* tbuf  = (float*)(ws + 74240);
  float* ybuf  = (float*)(ws + 74240 + CB);
  float* hbuf0 = (float*)(ws + 74240 + 2*CB);
  float* hbuf1 = (float*)(ws + 74240 + 3*CB);
  double* A    = (double*)(ws + 74240 + 4*CB);  // 2,433,536; 8.79 MB

  hipMemsetAsync(d_ws, 0, 2048, stream);        // lacc + nneg + logJ acc
  k_prep<<<1,256,0,stream>>>(x, nidx, tbuf);

  // CNN (conv1: gelu; conv2: res + fused next-pre / final logJ)
  k_conv<<<384,128,0,stream>>>(tbuf, w1[0], b1[0], nullptr, ybuf,
                               nullptr, nullptr, 2, 0, 1, 1.0f, 0.f);
  k_conv<<<384,128,0,stream>>>(ybuf, w2[0], b2[0], x, hbuf0,
                               tbuf, nullptr, 64, 2, 0, 1.0f,
                               0.70710678118654752f);
  k_conv<<<384,128,0,stream>>>(tbuf, w1[1], b1[1], nullptr, ybuf,
                               nullptr, nullptr, 64, 0, 1, 1.0f, 0.f);
  k_conv<<<384,128,0,stream>>>(ybuf, w2[1], b2[1], hbuf0, hbuf1,
                               tbuf, nullptr, 64, 1, 0, 1.0f,
                               0.57735026918962576f);
  k_conv<<<384,128,0,stream>>>(tbuf, w1[2], b1[2], nullptr, ybuf,
                               nullptr, nullptr, 64, 0, 1, 1.0f, 0.f);
  k_conv<<<384,128,0,stream>>>(ybuf, w2[2], b2[2], hbuf1, hbuf0,
                               tbuf, nullptr, 64, 1, 0, 1.0f, 0.5f);
  k_conv<<<384,128,0,stream>>>(tbuf, w1[3], b1[3], nullptr, ybuf,
                               nullptr, nullptr, 64, 0, 1, 1.0f, 0.f);
  k_conv<<<384,128,0,stream>>>(ybuf, w2[3], nullptr, hbuf0, hbuf1,
                               nullptr, logJa, 64, 1, 0,
                               0.44721359549995794f, 0.f);

  k_buildAvv<<<528,256,0,stream>>>(Fvv, nidx, A);
  k_buildAs<<<(24*PF_N+255)/256,256,0,stream>>>(Fhh, hbuf1, nidx, A);

  k_panelD0<<<1,256,0,stream>>>(A, hist0, lacc, nneg);
  for (int k = 0; k < 16; k++){
    double* hR = (k & 1) ? hist1 : hist0;
    double* hW = (k & 1) ? hist0 : hist1;
    const int m = PF_N - 64*(k+1);
    k_panelR<<<(m+3)/4,256,0,stream>>>(A, hR, k);
    const int nt = (m + 63) >> 6;
    k_trail<<<nt*(nt+1)/2,256,0,stream>>>(A, hR, hW, lacc, nneg, logJa,
                                          (float*)d_out, k, (k == 15) ? 1 : 0);
  }
}